// Round 3
// baseline (802.565 us; speedup 1.0000x reference)
//
#include <hip/hip_runtime.h>

// ---------------------------------------------------------------------------
// SVT channel/token mixing: dwconv (ch 0..63) + DTCWT fwd -> channel mix ->
// token mix -> DTCWT inv (ch 64..127).  B=256, H=W=28, C=128, Ch=64.
// Round 3: mixing kernels use wave-uniform weight indices (readfirstlane)
// so weight reads become scalar s_load through K$ (no LDS, no VALU slots).
// chmix: wave = one blk x 64 positions. tokmix: wave = one pp x 64 channels.
// ---------------------------------------------------------------------------

#define DI __device__ __forceinline__

__device__ constexpr float F_H0[13] = {
  -0.0017578f, 0.0f, 0.0222656f, -0.046875f, -0.0482422f, 0.296875f,
   0.5554688f, 0.296875f, -0.0482422f, -0.046875f, 0.0222656f, 0.0f, -0.0017578f};
__device__ constexpr float F_H1[19] = {
  -7.06e-05f, 0.0f, 0.0013419f, -0.0018834f, -0.0071568f, 0.023856f,
   0.0556431f, -0.0516881f, -0.2997576f, 0.5594308f, -0.2997576f, -0.0516881f,
   0.0556431f, 0.023856f, -0.0071568f, -0.0018834f, 0.0013419f, 0.0f, -7.06e-05f};
// g0 = h1 * sgn19 (+1 odd idx), g1 = -(h0 * sgn13) (+1 even idx)
__device__ constexpr float F_G0[19] = {
   7.06e-05f, 0.0f, -0.0013419f, -0.0018834f, 0.0071568f, 0.023856f,
  -0.0556431f, -0.0516881f, 0.2997576f, 0.5594308f, 0.2997576f, -0.0516881f,
  -0.0556431f, 0.023856f, 0.0071568f, -0.0018834f, -0.0013419f, 0.0f, 7.06e-05f};
__device__ constexpr float F_G1[13] = {
   0.0017578f, 0.0f, -0.0222656f, -0.046875f, 0.0482422f, 0.296875f,
  -0.5554688f, 0.296875f, 0.0482422f, -0.046875f, -0.0222656f, 0.0f, 0.0017578f};

DI constexpr int refl28(int i) { return i < 0 ? -1 - i : (i >= 28 ? 55 - i : i); }

#define S2C 0.70710678118654752f

// ---------------- K1: depthwise 3x3 conv (zero pad), channels 0..63 --------
__global__ __launch_bounds__(256) void k_dwconv(const float* __restrict__ x,
    const float* __restrict__ cw, const float* __restrict__ cb,
    float* __restrict__ out) {
  int tid = blockIdx.x * 256 + threadIdx.x;
  int c = tid & 63;
  int s = tid >> 6;                 // b*784 + h*28 + w
  int w = s % 28; int t2 = s / 28; int h = t2 % 28;
  const float* k = cw + c * 9;
  const float* xb = x + (size_t)s * 128 + c;
  float acc = cb[c];
  bool hm = h > 0, hp = h < 27, wm = w > 0, wp = w < 27;
  if (hm) {
    const float* r = xb - 28 * 128;
    if (wm) acc = fmaf(r[-128], k[0], acc);
    acc = fmaf(r[0], k[1], acc);
    if (wp) acc = fmaf(r[128], k[2], acc);
  }
  if (wm) acc = fmaf(xb[-128], k[3], acc);
  acc = fmaf(xb[0], k[4], acc);
  if (wp) acc = fmaf(xb[128], k[5], acc);
  if (hp) {
    const float* r = xb + 28 * 128;
    if (wm) acc = fmaf(r[-128], k[6], acc);
    acc = fmaf(r[0], k[7], acc);
    if (wp) acc = fmaf(r[128], k[8], acc);
  }
  out[(size_t)s * 128 + c] = acc;
}

// ---------------- K2: row filter (along W), line form ----------------------
__global__ __launch_bounds__(256) void k_rowfilt(const float* __restrict__ x,
    float* __restrict__ lo, float* __restrict__ hi) {
  int tid = threadIdx.x;
  int c = tid & 63;
  int line = blockIdx.x * 4 + (tid >> 6);     // line = b*28 + h, [0, 7168)
  const float* xp = x + (size_t)line * 28 * 128 + 64 + c;
  float v[28];
#pragma unroll
  for (int w = 0; w < 28; w++) v[w] = xp[w * 128];
  float* lp = lo + (size_t)line * 28 * 64 + c;
  float* hp = hi + (size_t)line * 28 * 64 + c;
#pragma unroll
  for (int w = 0; w < 28; w++) {
    float aLo = 0.f, aHi = 0.f;
#pragma unroll
    for (int t = 0; t < 13; t++) aLo = fmaf(F_H0[t], v[refl28(w - 6 + t)], aLo);
#pragma unroll
    for (int t = 0; t < 19; t++) aHi = fmaf(F_H1[t], v[refl28(w - 9 + t)], aHi);
    lp[w * 64] = aLo;
    hp[w * 64] = aHi;
  }
}

// ------- K3: column filter + q2c, line form (thread = (b, w2, c)) ----------
__global__ __launch_bounds__(256) void k_colfilt(const float* __restrict__ lo,
    const float* __restrict__ hi, const float* __restrict__ wll,
    float* __restrict__ xl, float* __restrict__ xhr, float* __restrict__ xhi) {
  __shared__ float swll[3584];                 // [(h*2+woff)*64 + c]
  int tid = threadIdx.x;
  int w2 = blockIdx.x >> 6;                    // 896 blocks: 64 per w2
  for (int j = tid; j < 3584; j += 256) {
    int cc = j & 63, t = j >> 6;               // t = h*2+woff
    int h = t >> 1, woff = t & 1;
    swll[j] = wll[cc * 784 + h * 28 + 2 * w2 + woff];
  }
  __syncthreads();
  int c = tid & 63;
  int unit = blockIdx.x * 4 + (tid >> 6);      // w2*256 + b
  int b = unit & 255;
  const int hs = 28 * 64;                      // h stride in lo/hi/xl
  int base_in = (b * 784 + 2 * w2) * 64 + c;
  float v0[28], v1[28];
#pragma unroll
  for (int h = 0; h < 28; h++) {
    v0[h] = lo[base_in + h * hs];
    v1[h] = lo[base_in + h * hs + 64];
  }
#pragma unroll
  for (int h = 0; h < 28; h++) {
    float a0 = 0.f, a1 = 0.f;
#pragma unroll
    for (int t = 0; t < 13; t++) {
      a0 = fmaf(F_H0[t], v0[refl28(h - 6 + t)], a0);
      a1 = fmaf(F_H0[t], v1[refl28(h - 6 + t)], a1);
    }
    int o = (b * 784 + h * 28 + 2 * w2) * 64 + c;
    xl[o]      = a0 * swll[(h * 2 + 0) * 64 + c];
    xl[o + 64] = a1 * swll[(h * 2 + 1) * 64 + c];
  }
  {
    float e0[28], e1[28];
#pragma unroll
    for (int h = 0; h < 28; h++) {
      float a0 = 0.f, a1 = 0.f;
#pragma unroll
      for (int t = 0; t < 19; t++) {
        a0 = fmaf(F_H1[t], v0[refl28(h - 9 + t)], a0);
        a1 = fmaf(F_H1[t], v1[refl28(h - 9 + t)], a1);
      }
      e0[h] = a0; e1[h] = a1;
    }
    int bb = (b * 6 * 196 + w2) * 64 + c;      // + band*12544 + i*896
#pragma unroll
    for (int i = 0; i < 14; i++) {
      float A = e0[2 * i], Bv = e1[2 * i], C = e0[2 * i + 1], D = e1[2 * i + 1];
      xhr[bb + 0 * 12544 + i * 896] = (A - D) * S2C;
      xhi[bb + 0 * 12544 + i * 896] = (Bv + C) * S2C;
      xhr[bb + 5 * 12544 + i * 896] = (A + D) * S2C;
      xhi[bb + 5 * 12544 + i * 896] = (Bv - C) * S2C;
    }
  }
#pragma unroll
  for (int h = 0; h < 28; h++) {
    v0[h] = hi[base_in + h * hs];
    v1[h] = hi[base_in + h * hs + 64];
  }
  {
    float e0[28], e1[28];
#pragma unroll
    for (int h = 0; h < 28; h++) {
      float a0 = 0.f, a1 = 0.f;
#pragma unroll
      for (int t = 0; t < 13; t++) {
        a0 = fmaf(F_H0[t], v0[refl28(h - 6 + t)], a0);
        a1 = fmaf(F_H0[t], v1[refl28(h - 6 + t)], a1);
      }
      e0[h] = a0; e1[h] = a1;
    }
    int bb = (b * 6 * 196 + w2) * 64 + c;
#pragma unroll
    for (int i = 0; i < 14; i++) {
      float A = e0[2 * i], Bv = e1[2 * i], C = e0[2 * i + 1], D = e1[2 * i + 1];
      xhr[bb + 2 * 12544 + i * 896] = (A - D) * S2C;
      xhi[bb + 2 * 12544 + i * 896] = (Bv + C) * S2C;
      xhr[bb + 3 * 12544 + i * 896] = (A + D) * S2C;
      xhi[bb + 3 * 12544 + i * 896] = (Bv - C) * S2C;
    }
  }
  {
    float e0[28], e1[28];
#pragma unroll
    for (int h = 0; h < 28; h++) {
      float a0 = 0.f, a1 = 0.f;
#pragma unroll
      for (int t = 0; t < 19; t++) {
        a0 = fmaf(F_H1[t], v0[refl28(h - 9 + t)], a0);
        a1 = fmaf(F_H1[t], v1[refl28(h - 9 + t)], a1);
      }
      e0[h] = a0; e1[h] = a1;
    }
    int bb = (b * 6 * 196 + w2) * 64 + c;
#pragma unroll
    for (int i = 0; i < 14; i++) {
      float A = e0[2 * i], Bv = e1[2 * i], C = e0[2 * i + 1], D = e1[2 * i + 1];
      xhr[bb + 1 * 12544 + i * 896] = (A - D) * S2C;
      xhi[bb + 1 * 12544 + i * 896] = (Bv + C) * S2C;
      xhr[bb + 4 * 12544 + i * 896] = (A + D) * S2C;
      xhi[bb + 4 * 12544 + i * 896] = (Bv - C) * S2C;
    }
  }
}

// ---------------- K4a: channel mix, scalar-weight form (in place) ----------
// Wave = one blk (uniform) x 64 positions. Weights via uniform float4 loads
// -> s_load_dwordx4 through K$, consumed as SGPR operands of v_fmac_f32.
__global__ __launch_bounds__(256) void k_chmix(float* __restrict__ xhr,
    float* __restrict__ xhi,
    const float* __restrict__ w1, const float* __restrict__ w2,
    const float* __restrict__ b1, const float* __restrict__ b2) {
  int tid = threadIdx.x;
  int lane = tid & 63;
  int blk = __builtin_amdgcn_readfirstlane(tid >> 6);   // 0..3 wave-uniform
  int p = blockIdx.x * 64 + lane;                       // position
  size_t base = (size_t)p * 64 + blk * 16;
  float xr[16], xi[16];
  {
    const float4* pr = (const float4*)(xhr + base);
    const float4* pi4 = (const float4*)(xhi + base);
#pragma unroll
    for (int j = 0; j < 4; j++) {
      float4 a = pr[j];
      xr[4 * j] = a.x; xr[4 * j + 1] = a.y; xr[4 * j + 2] = a.z; xr[4 * j + 3] = a.w;
      float4 bq = pi4[j];
      xi[4 * j] = bq.x; xi[4 * j + 1] = bq.y; xi[4 * j + 2] = bq.z; xi[4 * j + 3] = bq.w;
    }
  }
  float ar[16], ai[16];
  // ---- layer 1 ----
  {
    const float4* br4 = (const float4*)(b1 + blk * 16);
    const float4* bi4 = (const float4*)(b1 + 64 + blk * 16);
#pragma unroll
    for (int q = 0; q < 4; q++) {
      float4 r = br4[q], m = bi4[q];
      ar[4 * q] = r.x; ar[4 * q + 1] = r.y; ar[4 * q + 2] = r.z; ar[4 * q + 3] = r.w;
      ai[4 * q] = m.x; ai[4 * q + 1] = m.y; ai[4 * q + 2] = m.z; ai[4 * q + 3] = m.w;
    }
#pragma unroll
    for (int d = 0; d < 16; d++) {
      float xdr = xr[d], xdi = xi[d];
      const float4* wr4 = (const float4*)(w1 + blk * 256 + d * 16);
      const float4* wi4 = (const float4*)(w1 + 1024 + blk * 256 + d * 16);
#pragma unroll
      for (int q = 0; q < 4; q++) {
        float4 r = wr4[q], m = wi4[q];
        ar[4*q+0] = fmaf(xdr, r.x, ar[4*q+0]); ar[4*q+0] = fmaf(-xdi, m.x, ar[4*q+0]);
        ai[4*q+0] = fmaf(xdr, m.x, ai[4*q+0]); ai[4*q+0] = fmaf( xdi, r.x, ai[4*q+0]);
        ar[4*q+1] = fmaf(xdr, r.y, ar[4*q+1]); ar[4*q+1] = fmaf(-xdi, m.y, ar[4*q+1]);
        ai[4*q+1] = fmaf(xdr, m.y, ai[4*q+1]); ai[4*q+1] = fmaf( xdi, r.y, ai[4*q+1]);
        ar[4*q+2] = fmaf(xdr, r.z, ar[4*q+2]); ar[4*q+2] = fmaf(-xdi, m.z, ar[4*q+2]);
        ai[4*q+2] = fmaf(xdr, m.z, ai[4*q+2]); ai[4*q+2] = fmaf( xdi, r.z, ai[4*q+2]);
        ar[4*q+3] = fmaf(xdr, r.w, ar[4*q+3]); ar[4*q+3] = fmaf(-xdi, m.w, ar[4*q+3]);
        ai[4*q+3] = fmaf(xdr, m.w, ai[4*q+3]); ai[4*q+3] = fmaf( xdi, r.w, ai[4*q+3]);
      }
    }
#pragma unroll
    for (int k = 0; k < 16; k++) {
      xr[k] = fmaxf(ar[k], 0.f);              // y takes over x regs
      xi[k] = fmaxf(ai[k], 0.f);
    }
  }
  // ---- layer 2 ----
  {
    const float4* br4 = (const float4*)(b2 + blk * 16);
    const float4* bi4 = (const float4*)(b2 + 64 + blk * 16);
#pragma unroll
    for (int q = 0; q < 4; q++) {
      float4 r = br4[q], m = bi4[q];
      ar[4 * q] = r.x; ar[4 * q + 1] = r.y; ar[4 * q + 2] = r.z; ar[4 * q + 3] = r.w;
      ai[4 * q] = m.x; ai[4 * q + 1] = m.y; ai[4 * q + 2] = m.z; ai[4 * q + 3] = m.w;
    }
#pragma unroll
    for (int d = 0; d < 16; d++) {
      float xdr = xr[d], xdi = xi[d];
      const float4* wr4 = (const float4*)(w2 + blk * 256 + d * 16);
      const float4* wi4 = (const float4*)(w2 + 1024 + blk * 256 + d * 16);
#pragma unroll
      for (int q = 0; q < 4; q++) {
        float4 r = wr4[q], m = wi4[q];
        ar[4*q+0] = fmaf(xdr, r.x, ar[4*q+0]); ar[4*q+0] = fmaf(-xdi, m.x, ar[4*q+0]);
        ai[4*q+0] = fmaf(xdr, m.x, ai[4*q+0]); ai[4*q+0] = fmaf( xdi, r.x, ai[4*q+0]);
        ar[4*q+1] = fmaf(xdr, r.y, ar[4*q+1]); ar[4*q+1] = fmaf(-xdi, m.y, ar[4*q+1]);
        ai[4*q+1] = fmaf(xdr, m.y, ai[4*q+1]); ai[4*q+1] = fmaf( xdi, r.y, ai[4*q+1]);
        ar[4*q+2] = fmaf(xdr, r.z, ar[4*q+2]); ar[4*q+2] = fmaf(-xdi, m.z, ar[4*q+2]);
        ai[4*q+2] = fmaf(xdr, m.z, ai[4*q+2]); ai[4*q+2] = fmaf( xdi, r.z, ai[4*q+2]);
        ar[4*q+3] = fmaf(xdr, r.w, ar[4*q+3]); ar[4*q+3] = fmaf(-xdi, m.w, ar[4*q+3]);
        ai[4*q+3] = fmaf(xdr, m.w, ai[4*q+3]); ai[4*q+3] = fmaf( xdi, r.w, ai[4*q+3]);
      }
    }
  }
  float4* qr = (float4*)(xhr + base);
  float4* qi = (float4*)(xhi + base);
#pragma unroll
  for (int j = 0; j < 4; j++) {
    qr[j] = make_float4(ar[4 * j], ar[4 * j + 1], ar[4 * j + 2], ar[4 * j + 3]);
    qi[j] = make_float4(ai[4 * j], ai[4 * j + 1], ai[4 * j + 2], ai[4 * j + 3]);
  }
}

// ---------------- K4b: token mix, scalar-weight form (in place) ------------
// Wave = one pp (uniform h2) x 64 channels; 2 batch-half positions/thread.
__global__ __launch_bounds__(256) void k_tokmix(float* __restrict__ xhr,
    float* __restrict__ xhi,
    const float* __restrict__ wt1, const float* __restrict__ wt2,
    const float* __restrict__ bt1, const float* __restrict__ bt2) {
  int tid = threadIdx.x;
  int c = tid & 63;
  int pp = __builtin_amdgcn_readfirstlane(blockIdx.x * 4 + (tid >> 6)); // [0,10752)
  int h2 = pp % 14;
  int baseA = pp * 896 + c;           // 896 = 14*64
  int baseB = (pp + 10752) * 896 + c;
  float trA[14], tiA[14], trB[14], tiB[14];
#pragma unroll
  for (int d = 0; d < 14; d++) {
    trA[d] = xhr[baseA + d * 64]; tiA[d] = xhi[baseA + d * 64];
    trB[d] = xhr[baseB + d * 64]; tiB[d] = xhi[baseB + d * 64];
  }
  const float* W1 = wt1 + h2 * 196;   // + 2744 for imag
  const float* W2 = wt2 + h2 * 196;
  const float* B1 = bt1 + h2 * 14;    // + 196 for imag
  const float* B2 = bt2 + h2 * 14;
  float arA[14], aiA[14], arB[14], aiB[14];
  // ---- layer 1 ----
#pragma unroll
  for (int k = 0; k < 14; k++) {
    float br = B1[k], bi = B1[196 + k];
    arA[k] = br; aiA[k] = bi; arB[k] = br; aiB[k] = bi;
  }
#pragma unroll
  for (int d = 0; d < 14; d++) {
    float tAr = trA[d], tAi = tiA[d], tBr = trB[d], tBi = tiB[d];
    const float2* r2 = (const float2*)(W1 + d * 14);
    const float2* i2 = (const float2*)(W1 + 2744 + d * 14);
#pragma unroll
    for (int q = 0; q < 7; q++) {
      float2 wr = r2[q], wi = i2[q];
      int k = 2 * q;
      arA[k]   = fmaf(tAr, wr.x, arA[k]);   arA[k]   = fmaf(-tAi, wi.x, arA[k]);
      aiA[k]   = fmaf(tAr, wi.x, aiA[k]);   aiA[k]   = fmaf( tAi, wr.x, aiA[k]);
      arB[k]   = fmaf(tBr, wr.x, arB[k]);   arB[k]   = fmaf(-tBi, wi.x, arB[k]);
      aiB[k]   = fmaf(tBr, wi.x, aiB[k]);   aiB[k]   = fmaf( tBi, wr.x, aiB[k]);
      arA[k+1] = fmaf(tAr, wr.y, arA[k+1]); arA[k+1] = fmaf(-tAi, wi.y, arA[k+1]);
      aiA[k+1] = fmaf(tAr, wi.y, aiA[k+1]); aiA[k+1] = fmaf( tAi, wr.y, aiA[k+1]);
      arB[k+1] = fmaf(tBr, wr.y, arB[k+1]); arB[k+1] = fmaf(-tBi, wi.y, arB[k+1]);
      aiB[k+1] = fmaf(tBr, wi.y, aiB[k+1]); aiB[k+1] = fmaf( tBi, wr.y, aiB[k+1]);
    }
  }
#pragma unroll
  for (int k = 0; k < 14; k++) {
    trA[k] = fmaxf(arA[k], 0.f); tiA[k] = fmaxf(aiA[k], 0.f);
    trB[k] = fmaxf(arB[k], 0.f); tiB[k] = fmaxf(aiB[k], 0.f);
  }
  // ---- layer 2 ----
#pragma unroll
  for (int k = 0; k < 14; k++) {
    float br = B2[k], bi = B2[196 + k];
    arA[k] = br; aiA[k] = bi; arB[k] = br; aiB[k] = bi;
  }
#pragma unroll
  for (int d = 0; d < 14; d++) {
    float tAr = trA[d], tAi = tiA[d], tBr = trB[d], tBi = tiB[d];
    const float2* r2 = (const float2*)(W2 + d * 14);
    const float2* i2 = (const float2*)(W2 + 2744 + d * 14);
#pragma unroll
    for (int q = 0; q < 7; q++) {
      float2 wr = r2[q], wi = i2[q];
      int k = 2 * q;
      arA[k]   = fmaf(tAr, wr.x, arA[k]);   arA[k]   = fmaf(-tAi, wi.x, arA[k]);
      aiA[k]   = fmaf(tAr, wi.x, aiA[k]);   aiA[k]   = fmaf( tAi, wr.x, aiA[k]);
      arB[k]   = fmaf(tBr, wr.x, arB[k]);   arB[k]   = fmaf(-tBi, wi.x, arB[k]);
      aiB[k]   = fmaf(tBr, wi.x, aiB[k]);   aiB[k]   = fmaf( tBi, wr.x, aiB[k]);
      arA[k+1] = fmaf(tAr, wr.y, arA[k+1]); arA[k+1] = fmaf(-tAi, wi.y, arA[k+1]);
      aiA[k+1] = fmaf(tAr, wi.y, aiA[k+1]); aiA[k+1] = fmaf( tAi, wr.y, aiA[k+1]);
      arB[k+1] = fmaf(tBr, wr.y, arB[k+1]); arB[k+1] = fmaf(-tBi, wi.y, arB[k+1]);
      aiB[k+1] = fmaf(tBr, wi.y, aiB[k+1]); aiB[k+1] = fmaf( tBi, wr.y, aiB[k+1]);
    }
  }
#pragma unroll
  for (int k = 0; k < 14; k++) {
    xhr[baseA + k * 64] = arA[k]; xhi[baseA + k * 64] = aiA[k];
    xhr[baseB + k * 64] = arB[k]; xhi[baseB + k * 64] = aiB[k];
  }
}

// -------- K5: inverse column filter, line form (thread = (b, w, c)) --------
__global__ __launch_bounds__(256) void k_invcol(const float* __restrict__ xl,
    const float* __restrict__ xhr, const float* __restrict__ xhi,
    float* __restrict__ lo2, float* __restrict__ hi2) {
  int tid = threadIdx.x;
  int c = tid & 63;
  int line = blockIdx.x * 4 + (tid >> 6);      // line = b*28 + w
  int w = line % 28, b = line / 28;
  int w2 = w >> 1, pw = w & 1;
  const int hs = 28 * 64;
  int sp = (b * 784 + w) * 64 + c;
  int bb = (b * 6 * 196 + w2) * 64 + c;
  {
    float xlv[28], lhf[28];
#pragma unroll
    for (int h = 0; h < 28; h++) xlv[h] = xl[sp + h * hs];
    const float* p0r = xhr + bb + 0 * 12544;
    const float* p0i = xhi + bb + 0 * 12544;
    const float* p5r = xhr + bb + 5 * 12544;
    const float* p5i = xhi + bb + 5 * 12544;
#pragma unroll
    for (int i = 0; i < 14; i++) {
      float y0r = p0r[i * 896], y0i = p0i[i * 896];
      float y5r = p5r[i * 896], y5i = p5i[i * 896];
      float top, bot;
      if (pw) { top = y0i + y5i; bot = y5r - y0r; }
      else    { top = y0r + y5r; bot = y0i - y5i; }
      lhf[2 * i] = top * S2C; lhf[2 * i + 1] = bot * S2C;
    }
#pragma unroll
    for (int h = 0; h < 28; h++) {
      float acc = 0.f;
#pragma unroll
      for (int t = 0; t < 19; t++) acc = fmaf(F_G0[t], xlv[refl28(h - 9 + t)], acc);
#pragma unroll
      for (int t = 0; t < 13; t++) acc = fmaf(F_G1[t], lhf[refl28(h - 6 + t)], acc);
      lo2[sp + h * hs] = acc;
    }
  }
  {
    float hlC[28], hhD[28];
    const float* p2r = xhr + bb + 2 * 12544;
    const float* p2i = xhi + bb + 2 * 12544;
    const float* p3r = xhr + bb + 3 * 12544;
    const float* p3i = xhi + bb + 3 * 12544;
#pragma unroll
    for (int i = 0; i < 14; i++) {
      float y0r = p2r[i * 896], y0i = p2i[i * 896];
      float y5r = p3r[i * 896], y5i = p3i[i * 896];
      float top, bot;
      if (pw) { top = y0i + y5i; bot = y5r - y0r; }
      else    { top = y0r + y5r; bot = y0i - y5i; }
      hlC[2 * i] = top * S2C; hlC[2 * i + 1] = bot * S2C;
    }
    const float* p1r = xhr + bb + 1 * 12544;
    const float* p1i = xhi + bb + 1 * 12544;
    const float* p4r = xhr + bb + 4 * 12544;
    const float* p4i = xhi + bb + 4 * 12544;
#pragma unroll
    for (int i = 0; i < 14; i++) {
      float y0r = p1r[i * 896], y0i = p1i[i * 896];
      float y5r = p4r[i * 896], y5i = p4i[i * 896];
      float top, bot;
      if (pw) { top = y0i + y5i; bot = y5r - y0r; }
      else    { top = y0r + y5r; bot = y0i - y5i; }
      hhD[2 * i] = top * S2C; hhD[2 * i + 1] = bot * S2C;
    }
#pragma unroll
    for (int h = 0; h < 28; h++) {
      float acc = 0.f;
#pragma unroll
      for (int t = 0; t < 19; t++) acc = fmaf(F_G0[t], hlC[refl28(h - 9 + t)], acc);
#pragma unroll
      for (int t = 0; t < 13; t++) acc = fmaf(F_G1[t], hhD[refl28(h - 6 + t)], acc);
      hi2[sp + h * hs] = acc;
    }
  }
}

// ---------------- K6: inverse row filter, line form ------------------------
__global__ __launch_bounds__(256) void k_invrow(const float* __restrict__ lo2,
    const float* __restrict__ hi2, float* __restrict__ out) {
  int tid = threadIdx.x;
  int c = tid & 63;
  int line = blockIdx.x * 4 + (tid >> 6);      // line = b*28 + h
  const float* lr = lo2 + (size_t)line * 28 * 64 + c;
  const float* hr = hi2 + (size_t)line * 28 * 64 + c;
  float vl[28], vh[28];
#pragma unroll
  for (int w = 0; w < 28; w++) { vl[w] = lr[w * 64]; vh[w] = hr[w * 64]; }
  float* op = out + (size_t)line * 28 * 128 + 64 + c;
#pragma unroll
  for (int w = 0; w < 28; w++) {
    float acc = 0.f;
#pragma unroll
    for (int t = 0; t < 19; t++) acc = fmaf(F_G0[t], vl[refl28(w - 9 + t)], acc);
#pragma unroll
    for (int t = 0; t < 13; t++) acc = fmaf(F_G1[t], vh[refl28(w - 6 + t)], acc);
    op[w * 128] = acc;
  }
}

// ---------------------------------------------------------------------------
extern "C" void kernel_launch(void* const* d_in, const int* in_sizes, int n_in,
                              void* d_out, int out_size, void* d_ws, size_t ws_size,
                              hipStream_t stream) {
  const float* x    = (const float*)d_in[0];
  const float* cw   = (const float*)d_in[1];
  const float* cb   = (const float*)d_in[2];
  const float* wll  = (const float*)d_in[3];
  const float* wlh1 = (const float*)d_in[4];
  const float* wlh2 = (const float*)d_in[5];
  const float* blh1 = (const float*)d_in[6];
  const float* blh2 = (const float*)d_in[7];
  const float* wt1  = (const float*)d_in[8];
  const float* wt2  = (const float*)d_in[9];
  const float* bt1  = (const float*)d_in[10];
  const float* bt2  = (const float*)d_in[11];
  float* out = (float*)d_out;
  float* ws = (float*)d_ws;

  const size_t NSP = (size_t)256 * 784 * 64;     // 12,845,056
  const size_t NXH = (size_t)256 * 6 * 196 * 64; // 19,267,584
  float* lo  = ws;              // reused as lo2 after k_colfilt consumes it
  float* hi  = lo + NSP;        // reused as hi2
  float* xl  = hi + NSP;
  float* xhr = xl + NSP;
  float* xhi = xhr + NXH;       // total 308.3 MB

  dim3 blk(256);
  k_dwconv <<<50176, blk, 0, stream>>>(x, cw, cb, out);
  k_rowfilt<<<1792,  blk, 0, stream>>>(x, lo, hi);
  k_colfilt<<<896,   blk, 0, stream>>>(lo, hi, wll, xl, xhr, xhi);
  k_chmix  <<<4704,  blk, 0, stream>>>(xhr, xhi, wlh1, wlh2, blh1, blh2);
  k_tokmix <<<2688,  blk, 0, stream>>>(xhr, xhi, wt1, wt2, bt1, bt2);
  k_invcol <<<1792,  blk, 0, stream>>>(xl, xhr, xhi, lo, hi);
  k_invrow <<<1792,  blk, 0, stream>>>(lo, hi, out);
  (void)in_sizes; (void)n_in; (void)out_size; (void)ws_size;
}

// Round 4
// 728.445 us; speedup vs baseline: 1.1018x; 1.1018x over previous
//
#include <hip/hip_runtime.h>

// ---------------------------------------------------------------------------
// SVT channel/token mixing.  B=256, H=W=28, C=128, Ch=64.
// R4: k_fwd = fused row+col DTCWT fwd (LDS transpose per (b, cgroup8));
//     k_inv = fused col+row DTCWT inv; chmix = LDS-staged IO + scalar weights;
//     tokmix = r2 LDS-broadcast form (known good).
// ---------------------------------------------------------------------------

#define DI __device__ __forceinline__

__device__ constexpr float F_H0[13] = {
  -0.0017578f, 0.0f, 0.0222656f, -0.046875f, -0.0482422f, 0.296875f,
   0.5554688f, 0.296875f, -0.0482422f, -0.046875f, 0.0222656f, 0.0f, -0.0017578f};
__device__ constexpr float F_H1[19] = {
  -7.06e-05f, 0.0f, 0.0013419f, -0.0018834f, -0.0071568f, 0.023856f,
   0.0556431f, -0.0516881f, -0.2997576f, 0.5594308f, -0.2997576f, -0.0516881f,
   0.0556431f, 0.023856f, -0.0071568f, -0.0018834f, 0.0013419f, 0.0f, -7.06e-05f};
__device__ constexpr float F_G0[19] = {
   7.06e-05f, 0.0f, -0.0013419f, -0.0018834f, 0.0071568f, 0.023856f,
  -0.0556431f, -0.0516881f, 0.2997576f, 0.5594308f, 0.2997576f, -0.0516881f,
  -0.0556431f, 0.023856f, 0.0071568f, -0.0018834f, -0.0013419f, 0.0f, 7.06e-05f};
__device__ constexpr float F_G1[13] = {
   0.0017578f, 0.0f, -0.0222656f, -0.046875f, 0.0482422f, 0.296875f,
  -0.5554688f, 0.296875f, 0.0482422f, -0.046875f, -0.0222656f, 0.0f, 0.0017578f};

DI constexpr int refl28(int i) { return i < 0 ? -1 - i : (i >= 28 ? 55 - i : i); }

#define S2C 0.70710678118654752f
// LDS tile index: conflict-analyzed strides (h*285 + w*10 + c), c in [0,8)
#define LH(h, w, c) ((h) * 285 + (w) * 10 + (c))
#define LDS_TILE 7980

// ---------------- K1: depthwise 3x3 conv (zero pad), channels 0..63 --------
__global__ __launch_bounds__(256) void k_dwconv(const float* __restrict__ x,
    const float* __restrict__ cw, const float* __restrict__ cb,
    float* __restrict__ out) {
  int tid = blockIdx.x * 256 + threadIdx.x;
  int c = tid & 63;
  int s = tid >> 6;
  int w = s % 28; int t2 = s / 28; int h = t2 % 28;
  const float* k = cw + c * 9;
  const float* xb = x + (size_t)s * 128 + c;
  float acc = cb[c];
  bool hm = h > 0, hp = h < 27, wm = w > 0, wp = w < 27;
  if (hm) {
    const float* r = xb - 28 * 128;
    if (wm) acc = fmaf(r[-128], k[0], acc);
    acc = fmaf(r[0], k[1], acc);
    if (wp) acc = fmaf(r[128], k[2], acc);
  }
  if (wm) acc = fmaf(xb[-128], k[3], acc);
  acc = fmaf(xb[0], k[4], acc);
  if (wp) acc = fmaf(xb[128], k[5], acc);
  if (hp) {
    const float* r = xb + 28 * 128;
    if (wm) acc = fmaf(r[-128], k[6], acc);
    acc = fmaf(r[0], k[7], acc);
    if (wp) acc = fmaf(r[128], k[8], acc);
  }
  out[(size_t)s * 128 + c] = acc;
}

// ---------------- K2: fused forward DTCWT --------------------------------
DI void write_bands(float* __restrict__ xhr, float* __restrict__ xhi,
    int b, int bp, int bq, int S, int w2, int c64,
    const float* e0, const float* e1) {
#pragma unroll
  for (int ii = 0; ii < 7; ii++) {
    int i = 7 * S + ii;
    float A = e0[2 * ii], Bv = e1[2 * ii], C = e0[2 * ii + 1], D = e1[2 * ii + 1];
    int op = ((b * 6 + bp) * 196 + i * 14 + w2) * 64 + c64;
    int oq = ((b * 6 + bq) * 196 + i * 14 + w2) * 64 + c64;
    xhr[op] = (A - D) * S2C; xhi[op] = (Bv + C) * S2C;
    xhr[oq] = (A + D) * S2C; xhi[oq] = (Bv - C) * S2C;
  }
}

template <int S>
DI void fwd_phase2(const float* __restrict__ sL, const float* __restrict__ sH,
    int b, int cg, int w2, int c, const float* __restrict__ wll,
    float* __restrict__ xl, float* __restrict__ xhr, float* __restrict__ xhi) {
  int c64 = cg * 8 + c;
  float v0[28], v1[28];
#pragma unroll
  for (int h = 0; h < 28; h++) {
    v0[h] = sL[LH(h, 2 * w2, c)];
    v1[h] = sL[LH(h, 2 * w2 + 1, c)];
  }
  // ll -> xl (with wll), h in [14S, 14S+14)
#pragma unroll
  for (int j = 0; j < 14; j++) {
    int h = 14 * S + j;
    float a0 = 0.f, a1 = 0.f;
#pragma unroll
    for (int t = 0; t < 13; t++) {
      int idx = refl28(14 * S + j - 6 + t);
      a0 = fmaf(F_H0[t], v0[idx], a0);
      a1 = fmaf(F_H0[t], v1[idx], a1);
    }
    int o = (b * 784 + h * 28 + 2 * w2) * 64 + c64;
    xl[o]      = a0 * wll[c64 * 784 + h * 28 + 2 * w2];
    xl[o + 64] = a1 * wll[c64 * 784 + h * 28 + 2 * w2 + 1];
  }
  float e0[14], e1[14];
  // lh = h1(lo) -> bands 0,5
#pragma unroll
  for (int j = 0; j < 14; j++) {
    float a0 = 0.f, a1 = 0.f;
#pragma unroll
    for (int t = 0; t < 19; t++) {
      int idx = refl28(14 * S + j - 9 + t);
      a0 = fmaf(F_H1[t], v0[idx], a0);
      a1 = fmaf(F_H1[t], v1[idx], a1);
    }
    e0[j] = a0; e1[j] = a1;
  }
  write_bands(xhr, xhi, b, 0, 5, S, w2, c64, e0, e1);
  // reload hi rows
#pragma unroll
  for (int h = 0; h < 28; h++) {
    v0[h] = sH[LH(h, 2 * w2, c)];
    v1[h] = sH[LH(h, 2 * w2 + 1, c)];
  }
  // hl = h0(hi) -> bands 2,3
#pragma unroll
  for (int j = 0; j < 14; j++) {
    float a0 = 0.f, a1 = 0.f;
#pragma unroll
    for (int t = 0; t < 13; t++) {
      int idx = refl28(14 * S + j - 6 + t);
      a0 = fmaf(F_H0[t], v0[idx], a0);
      a1 = fmaf(F_H0[t], v1[idx], a1);
    }
    e0[j] = a0; e1[j] = a1;
  }
  write_bands(xhr, xhi, b, 2, 3, S, w2, c64, e0, e1);
  // hh = h1(hi) -> bands 1,4
#pragma unroll
  for (int j = 0; j < 14; j++) {
    float a0 = 0.f, a1 = 0.f;
#pragma unroll
    for (int t = 0; t < 19; t++) {
      int idx = refl28(14 * S + j - 9 + t);
      a0 = fmaf(F_H1[t], v0[idx], a0);
      a1 = fmaf(F_H1[t], v1[idx], a1);
    }
    e0[j] = a0; e1[j] = a1;
  }
  write_bands(xhr, xhi, b, 1, 4, S, w2, c64, e0, e1);
}

__global__ __launch_bounds__(256) void k_fwd(const float* __restrict__ x,
    const float* __restrict__ wll, float* __restrict__ xl,
    float* __restrict__ xhr, float* __restrict__ xhi) {
  __shared__ float sL[LDS_TILE];
  __shared__ float sH[LDS_TILE];
  int b = blockIdx.x >> 3;
  int cg = blockIdx.x & 7;
  int t = threadIdx.x;
  // phase 1: row filter, thread = (h, c8)
  if (t < 224) {
    int h = t >> 3, c = t & 7;
    const float* xp = x + ((size_t)(b * 28 + h) * 28) * 128 + 64 + cg * 8 + c;
    float v[28];
#pragma unroll
    for (int w = 0; w < 28; w++) v[w] = xp[w * 128];
#pragma unroll
    for (int w = 0; w < 28; w++) {
      float a = 0.f;
#pragma unroll
      for (int tt = 0; tt < 13; tt++) a = fmaf(F_H0[tt], v[refl28(w - 6 + tt)], a);
      sL[LH(h, w, c)] = a;
    }
#pragma unroll
    for (int w = 0; w < 28; w++) {
      float a = 0.f;
#pragma unroll
      for (int tt = 0; tt < 19; tt++) a = fmaf(F_H1[tt], v[refl28(w - 9 + tt)], a);
      sH[LH(h, w, c)] = a;
    }
  }
  __syncthreads();
  // phase 2: col filter + q2c, thread = (S, w2, c8); pure-S waves
  int S = t >> 7;
  int r = t & 127;
  if (r < 112) {
    int w2 = r >> 3, c = r & 7;
    if (S == 0) fwd_phase2<0>(sL, sH, b, cg, w2, c, wll, xl, xhr, xhi);
    else        fwd_phase2<1>(sL, sH, b, cg, w2, c, wll, xl, xhr, xhi);
  }
}

// ---------------- K3: channel mix (LDS-staged IO, scalar weights) ----------
__global__ __launch_bounds__(256) void k_chmix(float* __restrict__ xhr,
    float* __restrict__ xhi,
    const float* __restrict__ w1, const float* __restrict__ w2,
    const float* __restrict__ b1, const float* __restrict__ b2) {
  __shared__ float sR[64 * 66];
  __shared__ float sI[64 * 66];
  int tid = threadIdx.x;
  int pbase = blockIdx.x * 64;
  const float4* gr = (const float4*)(xhr + (size_t)pbase * 64);
  const float4* gi = (const float4*)(xhi + (size_t)pbase * 64);
  // stage in: 4096 floats each, pad-66 layout sR[p*66 + ch]
#pragma unroll
  for (int i = tid; i < 1024; i += 256) {
    int p = i >> 4, ch = (i & 15) * 4;
    int la = p * 66 + ch;
    float4 a = gr[i];
    *(float2*)(sR + la)     = make_float2(a.x, a.y);
    *(float2*)(sR + la + 2) = make_float2(a.z, a.w);
    float4 bq = gi[i];
    *(float2*)(sI + la)     = make_float2(bq.x, bq.y);
    *(float2*)(sI + la + 2) = make_float2(bq.z, bq.w);
  }
  __syncthreads();
  int lane = tid & 63;
  int blk = __builtin_amdgcn_readfirstlane(tid >> 6);   // wave-uniform 0..3
  int base = lane * 66 + blk * 16;
  float xr[16], xi[16];
#pragma unroll
  for (int j = 0; j < 8; j++) {
    float2 u = *(const float2*)(sR + base + 2 * j);
    xr[2 * j] = u.x; xr[2 * j + 1] = u.y;
    float2 v = *(const float2*)(sI + base + 2 * j);
    xi[2 * j] = v.x; xi[2 * j + 1] = v.y;
  }
  float ar[16], ai[16];
  // ---- layer 1 (weights: uniform address -> scalar loads) ----
  {
    const float* Wr = w1 + blk * 256;
    const float* Wi = w1 + 1024 + blk * 256;
#pragma unroll
    for (int k = 0; k < 16; k++) { ar[k] = b1[blk * 16 + k]; ai[k] = b1[64 + blk * 16 + k]; }
#pragma unroll
    for (int d = 0; d < 16; d++) {
      float xdr = xr[d], xdi = xi[d];
#pragma unroll
      for (int k = 0; k < 16; k++) {
        float wr = Wr[d * 16 + k], wi = Wi[d * 16 + k];
        ar[k] = fmaf(xdr, wr, ar[k]); ar[k] = fmaf(-xdi, wi, ar[k]);
        ai[k] = fmaf(xdr, wi, ai[k]); ai[k] = fmaf( xdi, wr, ai[k]);
      }
    }
#pragma unroll
    for (int k = 0; k < 16; k++) { xr[k] = fmaxf(ar[k], 0.f); xi[k] = fmaxf(ai[k], 0.f); }
  }
  // ---- layer 2 ----
  {
    const float* Wr = w2 + blk * 256;
    const float* Wi = w2 + 1024 + blk * 256;
#pragma unroll
    for (int k = 0; k < 16; k++) { ar[k] = b2[blk * 16 + k]; ai[k] = b2[64 + blk * 16 + k]; }
#pragma unroll
    for (int d = 0; d < 16; d++) {
      float xdr = xr[d], xdi = xi[d];
#pragma unroll
      for (int k = 0; k < 16; k++) {
        float wr = Wr[d * 16 + k], wi = Wi[d * 16 + k];
        ar[k] = fmaf(xdr, wr, ar[k]); ar[k] = fmaf(-xdi, wi, ar[k]);
        ai[k] = fmaf(xdr, wi, ai[k]); ai[k] = fmaf( xdi, wr, ai[k]);
      }
    }
  }
  __syncthreads();           // everyone done reading stage-in
#pragma unroll
  for (int j = 0; j < 8; j++) {
    *(float2*)(sR + base + 2 * j) = make_float2(ar[2 * j], ar[2 * j + 1]);
    *(float2*)(sI + base + 2 * j) = make_float2(ai[2 * j], ai[2 * j + 1]);
  }
  __syncthreads();
  float4* qr = (float4*)(xhr + (size_t)pbase * 64);
  float4* qi = (float4*)(xhi + (size_t)pbase * 64);
#pragma unroll
  for (int i = tid; i < 1024; i += 256) {
    int p = i >> 4, ch = (i & 15) * 4;
    int la = p * 66 + ch;
    float2 u0 = *(const float2*)(sR + la), u1 = *(const float2*)(sR + la + 2);
    qr[i] = make_float4(u0.x, u0.y, u1.x, u1.y);
    float2 v0 = *(const float2*)(sI + la), v1 = *(const float2*)(sI + la + 2);
    qi[i] = make_float4(v0.x, v0.y, v1.x, v1.y);
  }
}

// ---------------- K4: token mix (r2 LDS-broadcast form) --------------------
__global__ __launch_bounds__(256) void k_tokmix(float* __restrict__ xhr,
    float* __restrict__ xhi,
    const float* __restrict__ wt1, const float* __restrict__ wt2,
    const float* __restrict__ bt1, const float* __restrict__ bt2) {
  __shared__ __align__(16) float st1[5488];   // (h2*196+d*14+k)*2 + {r,i}
  __shared__ __align__(16) float st2[5488];
  __shared__ __align__(16) float sB1[392];
  __shared__ __align__(16) float sB2[392];
  int tid = threadIdx.x;
  for (int i = tid; i < 2744; i += 256) {
    st1[2 * i] = wt1[i]; st1[2 * i + 1] = wt1[2744 + i];
    st2[2 * i] = wt2[i]; st2[2 * i + 1] = wt2[2744 + i];
  }
  for (int i = tid; i < 196; i += 256) {
    sB1[2 * i] = bt1[i]; sB1[2 * i + 1] = bt1[196 + i];
    sB2[2 * i] = bt2[i]; sB2[2 * i + 1] = bt2[196 + i];
  }
  __syncthreads();
  int idx = blockIdx.x * 256 + tid;
  int c = idx & 63;
  int pp = idx >> 6;
  int h2 = pp % 14;
  int baseA = pp * 896 + c;
  int baseB = (pp + 10752) * 896 + c;
  float trA[14], tiA[14], trB[14], tiB[14];
#pragma unroll
  for (int d = 0; d < 14; d++) {
    trA[d] = xhr[baseA + d * 64]; tiA[d] = xhi[baseA + d * 64];
    trB[d] = xhr[baseB + d * 64]; tiB[d] = xhi[baseB + d * 64];
  }
  const float* w1 = st1 + h2 * 392;
  const float* w2 = st2 + h2 * 392;
  const float* bb1 = sB1 + h2 * 28;
  const float* bb2 = sB2 + h2 * 28;
  float mrA[14], miA[14], mrB[14], miB[14];
#pragma unroll
  for (int k = 0; k < 14; k++) {
    float br = bb1[2 * k], bi = bb1[2 * k + 1];
    float arA = br, aiA = bi, arB = br, aiB = bi;
#pragma unroll
    for (int d = 0; d < 14; d++) {
      float wr = w1[(d * 14 + k) * 2], wi = w1[(d * 14 + k) * 2 + 1];
      arA = fmaf(trA[d], wr, arA); arA = fmaf(-tiA[d], wi, arA);
      aiA = fmaf(trA[d], wi, aiA); aiA = fmaf(tiA[d], wr, aiA);
      arB = fmaf(trB[d], wr, arB); arB = fmaf(-tiB[d], wi, arB);
      aiB = fmaf(trB[d], wi, aiB); aiB = fmaf(tiB[d], wr, aiB);
    }
    mrA[k] = fmaxf(arA, 0.f); miA[k] = fmaxf(aiA, 0.f);
    mrB[k] = fmaxf(arB, 0.f); miB[k] = fmaxf(aiB, 0.f);
  }
#pragma unroll
  for (int k = 0; k < 14; k++) {
    float br = bb2[2 * k], bi = bb2[2 * k + 1];
    float arA = br, aiA = bi, arB = br, aiB = bi;
#pragma unroll
    for (int d = 0; d < 14; d++) {
      float wr = w2[(d * 14 + k) * 2], wi = w2[(d * 14 + k) * 2 + 1];
      arA = fmaf(mrA[d], wr, arA); arA = fmaf(-miA[d], wi, arA);
      aiA = fmaf(mrA[d], wi, aiA); aiA = fmaf(miA[d], wr, aiA);
      arB = fmaf(mrB[d], wr, arB); arB = fmaf(-miB[d], wi, arB);
      aiB = fmaf(mrB[d], wi, aiB); aiB = fmaf(miB[d], wr, aiB);
    }
    xhr[baseA + k * 64] = arA; xhi[baseA + k * 64] = aiA;
    xhr[baseB + k * 64] = arB; xhi[baseB + k * 64] = aiB;
  }
}

// ---------------- K5: fused inverse DTCWT ---------------------------------
__global__ __launch_bounds__(256) void k_inv(const float* __restrict__ xl,
    const float* __restrict__ xhr, const float* __restrict__ xhi,
    float* __restrict__ out) {
  __shared__ float sL[LDS_TILE];
  __shared__ float sH[LDS_TILE];
  int b = blockIdx.x >> 3;
  int cg = blockIdx.x & 7;
  int t = threadIdx.x;
  // phase 1: inverse column filter, thread = (w, c8), writes LDS columns
  if (t < 224) {
    int w = t >> 3, c = t & 7;
    int c64 = cg * 8 + c;
    int w2 = w >> 1, pw = w & 1;
    int sp = (b * 784 + w) * 64 + c64;          // + h*1792
    int bb = (b * 6 * 196 + w2) * 64 + c64;     // + band*12544 + i*896
    {
      float xlv[28], lhf[28];
#pragma unroll
      for (int h = 0; h < 28; h++) xlv[h] = xl[sp + h * 1792];
      const float* p0r = xhr + bb + 0 * 12544;
      const float* p0i = xhi + bb + 0 * 12544;
      const float* p5r = xhr + bb + 5 * 12544;
      const float* p5i = xhi + bb + 5 * 12544;
#pragma unroll
      for (int i = 0; i < 14; i++) {
        float y0r = p0r[i * 896], y0i = p0i[i * 896];
        float y5r = p5r[i * 896], y5i = p5i[i * 896];
        float top = pw ? (y0i + y5i) : (y0r + y5r);
        float bot = pw ? (y5r - y0r) : (y0i - y5i);
        lhf[2 * i] = top * S2C; lhf[2 * i + 1] = bot * S2C;
      }
#pragma unroll
      for (int h = 0; h < 28; h++) {
        float acc = 0.f;
#pragma unroll
        for (int tt = 0; tt < 19; tt++) acc = fmaf(F_G0[tt], xlv[refl28(h - 9 + tt)], acc);
#pragma unroll
        for (int tt = 0; tt < 13; tt++) acc = fmaf(F_G1[tt], lhf[refl28(h - 6 + tt)], acc);
        sL[LH(h, w, c)] = acc;
      }
    }
    {
      float hlC[28], hhD[28];
      const float* p2r = xhr + bb + 2 * 12544;
      const float* p2i = xhi + bb + 2 * 12544;
      const float* p3r = xhr + bb + 3 * 12544;
      const float* p3i = xhi + bb + 3 * 12544;
#pragma unroll
      for (int i = 0; i < 14; i++) {
        float y0r = p2r[i * 896], y0i = p2i[i * 896];
        float y5r = p3r[i * 896], y5i = p3i[i * 896];
        float top = pw ? (y0i + y5i) : (y0r + y5r);
        float bot = pw ? (y5r - y0r) : (y0i - y5i);
        hlC[2 * i] = top * S2C; hlC[2 * i + 1] = bot * S2C;
      }
      const float* p1r = xhr + bb + 1 * 12544;
      const float* p1i = xhi + bb + 1 * 12544;
      const float* p4r = xhr + bb + 4 * 12544;
      const float* p4i = xhi + bb + 4 * 12544;
#pragma unroll
      for (int i = 0; i < 14; i++) {
        float y0r = p1r[i * 896], y0i = p1i[i * 896];
        float y5r = p4r[i * 896], y5i = p4i[i * 896];
        float top = pw ? (y0i + y5i) : (y0r + y5r);
        float bot = pw ? (y5r - y0r) : (y0i - y5i);
        hhD[2 * i] = top * S2C; hhD[2 * i + 1] = bot * S2C;
      }
#pragma unroll
      for (int h = 0; h < 28; h++) {
        float acc = 0.f;
#pragma unroll
        for (int tt = 0; tt < 19; tt++) acc = fmaf(F_G0[tt], hlC[refl28(h - 9 + tt)], acc);
#pragma unroll
        for (int tt = 0; tt < 13; tt++) acc = fmaf(F_G1[tt], hhD[refl28(h - 6 + tt)], acc);
        sH[LH(h, w, c)] = acc;
      }
    }
  }
  __syncthreads();
  // phase 2: inverse row filter, thread = (h, c8)
  if (t < 224) {
    int h = t >> 3, c = t & 7;
    int c64 = cg * 8 + c;
    float vl[28], vh[28];
#pragma unroll
    for (int w = 0; w < 28; w++) { vl[w] = sL[LH(h, w, c)]; vh[w] = sH[LH(h, w, c)]; }
    float* op = out + ((size_t)(b * 28 + h) * 28) * 128 + 64 + c64;
#pragma unroll
    for (int w = 0; w < 28; w++) {
      float acc = 0.f;
#pragma unroll
      for (int tt = 0; tt < 19; tt++) acc = fmaf(F_G0[tt], vl[refl28(w - 9 + tt)], acc);
#pragma unroll
      for (int tt = 0; tt < 13; tt++) acc = fmaf(F_G1[tt], vh[refl28(w - 6 + tt)], acc);
      op[w * 128] = acc;
    }
  }
}

// ---------------------------------------------------------------------------
extern "C" void kernel_launch(void* const* d_in, const int* in_sizes, int n_in,
                              void* d_out, int out_size, void* d_ws, size_t ws_size,
                              hipStream_t stream) {
  const float* x    = (const float*)d_in[0];
  const float* cw   = (const float*)d_in[1];
  const float* cb   = (const float*)d_in[2];
  const float* wll  = (const float*)d_in[3];
  const float* wlh1 = (const float*)d_in[4];
  const float* wlh2 = (const float*)d_in[5];
  const float* blh1 = (const float*)d_in[6];
  const float* blh2 = (const float*)d_in[7];
  const float* wt1  = (const float*)d_in[8];
  const float* wt2  = (const float*)d_in[9];
  const float* bt1  = (const float*)d_in[10];
  const float* bt2  = (const float*)d_in[11];
  float* out = (float*)d_out;
  float* ws = (float*)d_ws;

  const size_t NSP = (size_t)256 * 784 * 64;     // 12,845,056
  const size_t NXH = (size_t)256 * 6 * 196 * 64; // 19,267,584
  float* xl  = ws;
  float* xhr = xl + NSP;
  float* xhi = xhr + NXH;       // total 196 MB

  dim3 blk(256);
  k_dwconv<<<50176, blk, 0, stream>>>(x, cw, cb, out);
  k_fwd   <<<2048,  blk, 0, stream>>>(x, wll, xl, xhr, xhi);
  k_chmix <<<4704,  blk, 0, stream>>>(xhr, xhi, wlh1, wlh2, blh1, blh2);
  k_tokmix<<<2688,  blk, 0, stream>>>(xhr, xhi, wt1, wt2, bt1, bt2);
  k_inv   <<<2048,  blk, 0, stream>>>(xl, xhr, xhi, out);
  (void)in_sizes; (void)n_in; (void)out_size; (void)ws_size;
}